// Round 6
// baseline (1764.823 us; speedup 1.0000x reference)
//
#include <hip/hip_runtime.h>

#define N_NODES 100000
#define N_PAIRS 1600000
#define EDGE_NUM 30000
#define D 64
#define NEG_SLOPE 0.2f
#define TN 16   // nodes staged per block in x0 gemm

// slot-partition params: bucket = slot >> SHIFT, capacity 1<<SHIFT recs
#define NBE 49   // ceil(1.6M / 32768)  e-list buckets (window 128 KB)
#define SHE 15
#define PBE 17   // payload bits: vertex id < 131072
#define NBV 25   // ceil(1.6M / 65536)  v-list buckets (window 256 KB)
#define SHV 16
#define PBV 15   // payload bits: edge id < 32768

// ---------------------------------------------------------------------------
// Kernel 1: X0 = X @ Ww[0]^T + Wb[0]  -> d_out (vertex gather adds onto it)
// ---------------------------------------------------------------------------
__global__ __launch_bounds__(256) void x0_kernel(
    const float* __restrict__ X, const float* __restrict__ Ww,
    const float* __restrict__ Wb, float* __restrict__ out0)
{
    __shared__ float xs[TN][D];
    const int wave = threadIdx.x >> 6;
    const int lane = threadIdx.x & 63;

    float w[64];
    const float* wrow = Ww + (size_t)lane * 64;
    #pragma unroll
    for (int i = 0; i < 64; i += 4) {
        float4 v = *(const float4*)(wrow + i);
        w[i] = v.x; w[i+1] = v.y; w[i+2] = v.z; w[i+3] = v.w;
    }
    const float b = Wb[lane];

    for (int base = blockIdx.x * TN; base < N_NODES; base += gridDim.x * TN) {
        const int ntile = min(TN, N_NODES - base);
        __syncthreads();
        {
            int n = threadIdx.x >> 4;
            int c = (threadIdx.x & 15) << 2;
            if (n < ntile)
                *(float4*)&xs[n][c] = *(const float4*)&X[(size_t)(base + n) * D + c];
        }
        __syncthreads();
        #pragma unroll
        for (int q = 0; q < 4; ++q) {
            const int n = wave * 4 + q;
            if (n < ntile) {
                float acc = 0.f;
                #pragma unroll
                for (int i = 0; i < 64; ++i) acc = fmaf(xs[n][i], w[i], acc);
                out0[(size_t)(base + n) * D + lane] = acc + b;
            }
        }
    }
}

// ---------------------------------------------------------------------------
// CSR build: histograms -> 2-block scan -> slot-partition fill (R4/R5)
// ---------------------------------------------------------------------------
__global__ __launch_bounds__(256) void hist2_kernel(
    const int* __restrict__ edges, const int* __restrict__ vertex,
    int* __restrict__ ecnt, int* __restrict__ vcnt, int n)
{
    const int i = blockIdx.x * blockDim.x + threadIdx.x;
    if (i < n) {
        atomicAdd(&ecnt[edges[i]], 1);
        atomicAdd(&vcnt[vertex[i]], 1);
    }
}

__device__ void scan_body(const int* cnt, int* off, int* cur, int n)
{
    __shared__ int wsum[16];
    __shared__ int s_carry;
    if (threadIdx.x == 0) s_carry = 0;
    __syncthreads();
    const int lane = threadIdx.x & 63;
    const int wave = threadIdx.x >> 6;

    for (int base = 0; base < n; base += 4096) {
        const int i0 = base + threadIdx.x * 4;
        int x0 = 0, x1 = 0, x2 = 0, x3 = 0;
        if (i0 + 3 < n) {
            int4 v = *(const int4*)&cnt[i0];
            x0 = v.x; x1 = v.y; x2 = v.z; x3 = v.w;
        } else {
            if (i0     < n) x0 = cnt[i0];
            if (i0 + 1 < n) x1 = cnt[i0 + 1];
            if (i0 + 2 < n) x2 = cnt[i0 + 2];
            if (i0 + 3 < n) x3 = cnt[i0 + 3];
        }
        const int tsum = x0 + x1 + x2 + x3;
        int sc = tsum;
        #pragma unroll
        for (int s = 1; s < 64; s <<= 1) {
            int y = __shfl_up(sc, s);
            if (lane >= s) sc += y;
        }
        if (lane == 63) wsum[wave] = sc;
        __syncthreads();
        int wbase = 0;
        for (int w = 0; w < wave; ++w) wbase += wsum[w];
        const int carry = s_carry;
        const int excl = carry + wbase + sc - tsum;
        const int o0 = excl, o1 = o0 + x0, o2 = o1 + x1, o3 = o2 + x2;
        if (i0 + 3 < n) {
            *(int4*)&off[i0] = make_int4(o0, o1, o2, o3);
            *(int4*)&cur[i0] = make_int4(o0, o1, o2, o3);
        } else {
            if (i0     < n) { off[i0]   = o0; cur[i0]   = o0; }
            if (i0 + 1 < n) { off[i0+1] = o1; cur[i0+1] = o1; }
            if (i0 + 2 < n) { off[i0+2] = o2; cur[i0+2] = o2; }
            if (i0 + 3 < n) { off[i0+3] = o3; cur[i0+3] = o3; }
        }
        __syncthreads();
        if (threadIdx.x == 1023) s_carry = carry + wbase + sc;
        __syncthreads();
    }
    if (threadIdx.x == 0) off[n] = s_carry;
}

__global__ __launch_bounds__(1024) void scan2_kernel(
    int* ecnt, int* eoff, int* vcnt, int* voff)
{
    if (blockIdx.x == 0) scan_body(ecnt, eoff, ecnt, EDGE_NUM);
    else                 scan_body(vcnt, voff, vcnt, N_NODES);
}

// Pass A: compute dest slot via atomic bump, pack (slotIn, payload) into 32b
// UNSIGNED (R5 fix: slotIn<<17 can set bit31; signed >> in pass B then
// sign-extended -> OOB write -> R4 crash), stage in per-block LDS bucket
// buffers, flush 16-rec chunks = one aligned 64B line per global-cursor grant
// -> zero write amplification in the main loop.
template <int NB, int SHIFT, int PAYBITS>
__global__ __launch_bounds__(256) void fillA_kernel(
    const int* __restrict__ keys, const int* __restrict__ pay,
    int* __restrict__ cur, int* __restrict__ gcur,
    unsigned int* __restrict__ stage)
{
    __shared__ unsigned int lbuf[NB * 272];   // residual(<=15) + 256 inserts
    __shared__ int lcnt[NB];
    const int lane = threadIdx.x & 63;
    const int wave = threadIdx.x >> 6;
    for (int b = threadIdx.x; b < NB; b += 256) lcnt[b] = 0;
    __syncthreads();

    const int stride = gridDim.x * 256;
    const int base0 = blockIdx.x * 256 + threadIdx.x;
    const int nIter = (N_PAIRS + stride - 1) / stride;

    for (int it = 0; it < nIter; ++it) {
        const int i = base0 + it * stride;
        if (i < N_PAIRS) {
            const int k = keys[i];
            const unsigned int p = (unsigned int)pay[i];
            const int slot = atomicAdd(&cur[k], 1);
            const int b = slot >> SHIFT;
            const unsigned int rec =
                ((unsigned int)(slot & ((1 << SHIFT) - 1)) << PAYBITS) | p;
            const int pos = atomicAdd(&lcnt[b], 1);
            lbuf[b * 272 + pos] = rec;
        }
        __syncthreads();
        // flush full 16-rec (64B) chunks; residual <16 stays at [0, c-nf)
        for (int b = wave; b < NB; b += 4) {
            const int c = lcnt[b];
            const int nf = c & ~15;
            if (nf) {
                int gb = 0;
                if (lane == 0) gb = atomicAdd(&gcur[b], nf);
                gb = __shfl(gb, 0);
                unsigned int* dst = stage + ((size_t)b << SHIFT) + gb;
                const unsigned int* src = &lbuf[b * 272 + (c - nf)];
                for (int k2 = lane; k2 < nf; k2 += 64) dst[k2] = src[k2];
                if (lane == 0) lcnt[b] = c - nf;
            }
        }
        __syncthreads();
    }
    // final residual flush (partial lines, bounded: NB*15 recs per block)
    for (int b = wave; b < NB; b += 4) {
        const int c = lcnt[b];
        if (c) {
            int gb = 0;
            if (lane == 0) gb = atomicAdd(&gcur[b], c);
            gb = __shfl(gb, 0);
            unsigned int* dst = stage + ((size_t)b << SHIFT) + gb;
            for (int k2 = lane; k2 < c; k2 += 64) dst[k2] = lbuf[b * 272 + k2];
        }
    }
}

// Pass B: one block per bucket; coalesced rec reads, scatter confined to a
// 128/256 KB window touched by a single block (single XCD, short lifetime)
// -> lines merge fully in L2 before writeback. Unsigned unpack (R5 fix).
template <int SHIFT, int PAYBITS>
__global__ __launch_bounds__(512) void fillB_kernel(
    const unsigned int* __restrict__ stage, const int* __restrict__ gcur,
    int* __restrict__ outlist)
{
    const int b = blockIdx.x;
    const int cnt = gcur[b];
    const size_t base = (size_t)b << SHIFT;
    for (int i = threadIdx.x; i < cnt; i += 512) {
        const unsigned int rec = stage[base + i];
        outlist[base + (rec >> PAYBITS)] =
            (int)(rec & ((1u << PAYBITS) - 1u));
    }
}

// ---------------------------------------------------------------------------
// Kernel: per-edge gather. One wave per edge. Indices loaded 64-at-a-time
// per lane (vector load), broadcast via __shfl; inner loop manually unrolled
// 8-wide so 8 independent X-row gathers are in flight per wave.
// R2 (kept, confirmed ~-87us): W_t staged in LDS (padded stride 65).
// ---------------------------------------------------------------------------
__global__ __launch_bounds__(256) void edge_gather_kernel(
    const float* __restrict__ X, const float* __restrict__ degV,
    const float* __restrict__ Ww, const float* __restrict__ Wb,
    const int* __restrict__ eoff, const int* __restrict__ evlist,
    float* __restrict__ Xe)
{
    __shared__ float Wlds[64 * 65];
    __shared__ float aLds[4][64];
    const int lane = threadIdx.x & 63;
    const int wave = threadIdx.x >> 6;
    const int e = blockIdx.x * 4 + wave;
    const int t = (e >= 10000) + (e >= 20000);   // uniform per block

    {
        const float* wsrc = Ww + (size_t)(t + 1) * 4096;
        for (int idx = threadIdx.x * 4; idx < 4096; idx += 256 * 4) {
            float4 v = *(const float4*)(wsrc + idx);
            const int r = idx >> 6, c = idx & 63;
            float* dst = &Wlds[r * 65 + c];
            dst[0] = v.x; dst[1] = v.y; dst[2] = v.z; dst[3] = v.w;
        }
    }
    __syncthreads();

    const float b = Wb[(t + 1) * 64 + lane];
    const int start = eoff[e], end = eoff[e + 1];
    const float* __restrict__ degt = degV + (size_t)t * N_NODES;
    const float* __restrict__ Xl = X + lane;

    float acc0 = 0.f, acc1 = 0.f, sdeg = 0.f;
    for (int j0 = start; j0 < end; j0 += 64) {
        const int m = min(64, end - j0);
        const int vv = (lane < m) ? evlist[j0 + lane] : 0;
        int j = 0;
        for (; j + 8 <= m; j += 8) {
            int v[8];
            #pragma unroll
            for (int u = 0; u < 8; ++u) v[u] = __shfl(vv, j + u);
            float f[8], s[8];
            #pragma unroll
            for (int u = 0; u < 8; ++u) f[u] = Xl[(size_t)v[u] * D];
            #pragma unroll
            for (int u = 0; u < 8; ++u) s[u] = degt[v[u]];
            #pragma unroll
            for (int u = 0; u < 8; u += 2) {
                acc0 = fmaf(s[u],     f[u],     acc0);
                acc1 = fmaf(s[u + 1], f[u + 1], acc1);
                sdeg += s[u] + s[u + 1];
            }
        }
        for (; j < m; ++j) {
            const int v = __shfl(vv, j);
            const float s = degt[v];
            acc0 = fmaf(s, Xl[(size_t)v * D], acc0);
            sdeg += s;
        }
    }
    aLds[wave][lane] = acc0 + acc1;

    float r = 0.f;
    #pragma unroll
    for (int i = 0; i < 64; ++i)
        r = fmaf(aLds[wave][i], Wlds[lane * 65 + i], r);
    r += sdeg * b;
    const int k = max(end - start, 1);
    Xe[(size_t)e * D + lane] = r / (float)k;
}

// ---------------------------------------------------------------------------
// Kernel: per-vertex gather + X0 add + L2 normalize + leaky relu (in place)
// ---------------------------------------------------------------------------
__global__ __launch_bounds__(256) void vertex_gather_kernel(
    const float* __restrict__ Xe, const int* __restrict__ voff,
    const int* __restrict__ velist, float* __restrict__ out)
{
    const int v = blockIdx.x * 4 + (threadIdx.x >> 6);
    const int lane = threadIdx.x & 63;
    const int start = voff[v], end = voff[v + 1];
    const float* __restrict__ Xel = Xe + lane;

    float acc0 = out[(size_t)v * D + lane];   // X0
    float acc1 = 0.f;
    for (int j0 = start; j0 < end; j0 += 64) {
        const int m = min(64, end - j0);
        const int ee = (lane < m) ? velist[j0 + lane] : 0;
        int j = 0;
        for (; j + 8 <= m; j += 8) {
            int e[8];
            #pragma unroll
            for (int u = 0; u < 8; ++u) e[u] = __shfl(ee, j + u);
            float f[8];
            #pragma unroll
            for (int u = 0; u < 8; ++u) f[u] = Xel[(size_t)e[u] * D];
            #pragma unroll
            for (int u = 0; u < 8; u += 2) {
                acc0 += f[u];
                acc1 += f[u + 1];
            }
        }
        for (; j < m; ++j) {
            const int e = __shfl(ee, j);
            acc0 += Xel[(size_t)e * D];
        }
    }
    const float acc = acc0 + acc1;

    float ss = acc * acc;
    #pragma unroll
    for (int off = 1; off < 64; off <<= 1) ss += __shfl_xor(ss, off);
    const float rn = sqrtf(ss);
    const float scale = (rn == 0.f) ? 0.f : 1.f / rn;
    const float y = acc * scale;
    out[(size_t)v * D + lane] = (y > 0.f) ? y : NEG_SLOPE * y;
}

// ---------------------------------------------------------------------------
extern "C" void kernel_launch(void* const* d_in, const int* in_sizes, int n_in,
                              void* d_out, int out_size, void* d_ws, size_t ws_size,
                              hipStream_t stream)
{
    const float* X      = (const float*)d_in[0];   // (100000, 64)
    const float* degV   = (const float*)d_in[1];   // (3, 100000, 1)
    const float* Ww     = (const float*)d_in[2];   // (4, 64, 64)
    const float* Wb     = (const float*)d_in[3];   // (4, 64)
    const int*   vertex = (const int*)d_in[4];     // (1600000,)
    const int*   edges  = (const int*)d_in[5];     // (1600000,)
    float* out = (float*)d_out;                    // (100000, 64)

    // workspace layout (~21.5 MB, unchanged footprint)
    float* Xe    = (float*)d_ws;              // 1,920,000 f32 (7.68 MB)
    unsigned int* stage = (unsigned int*)d_ws; // overlays Xe: max 6.55 MB,
                                               // dead before edge_gather
    int*   ib    = (int*)(Xe + 1920000);
    int* eoff    = ib;                        // 30001 (pad to 30004)
    int* ecur    = ib + 30004;                // 30000 (pad to 30004)
    int* voff    = ib + 60008;                // 100001 (pad to 100004)
    int* vcur    = ib + 160012;               // 100000
    int* gcurE   = ib + 260012;               // 49 (pad to 64)
    int* gcurV   = ib + 260076;               // 25 (pad to 36)
    int* evlist  = ib + 260112;               // 1,600,000
    int* velist  = ib + 1860112;              // 1,600,000

    // zero counters (eoff..gcurV inclusive)
    hipMemsetAsync(ib, 0, (size_t)260112 * sizeof(int), stream);

    x0_kernel<<<1024, 256, 0, stream>>>(X, Ww, Wb, out);

    const int pb = (N_PAIRS + 255) / 256;     // 6250
    hist2_kernel<<<pb, 256, 0, stream>>>(edges, vertex, ecur, vcur, N_PAIRS);
    scan2_kernel<<<2, 1024, 0, stream>>>(ecur, eoff, vcur, voff);

    // stage buffer reused e-pass then v-pass (forces A-e,B-e,A-v,B-v order)
    fillA_kernel<NBE, SHE, PBE><<<512, 256, 0, stream>>>(
        edges, vertex, ecur, gcurE, stage);
    fillB_kernel<SHE, PBE><<<NBE, 512, 0, stream>>>(stage, gcurE, evlist);
    fillA_kernel<NBV, SHV, PBV><<<512, 256, 0, stream>>>(
        vertex, edges, vcur, gcurV, stage);
    fillB_kernel<SHV, PBV><<<NBV, 512, 0, stream>>>(stage, gcurV, velist);

    edge_gather_kernel<<<EDGE_NUM / 4, 256, 0, stream>>>(
        X, degV, Ww, Wb, eoff, evlist, Xe);

    vertex_gather_kernel<<<N_NODES / 4, 256, 0, stream>>>(Xe, voff, velist, out);
}

// Round 7
// 484.166 us; speedup vs baseline: 3.6451x; 3.6451x over previous
//
#include <hip/hip_runtime.h>

#define N_NODES 100000
#define N_PAIRS 1600000
#define EDGE_NUM 30000
#define D 64
#define NEG_SLOPE 0.2f
#define TN 16    // nodes staged per block in x0 gemm
#define NG 128   // pair-chunks for the XCD-pinned fill (grid = 8*NG)

#define HBLK 6250   // hist blocks in fused kernel (pairs/256)
#define XBLK 1024   // x0 blocks in fused kernel
#define NCE 8       // e-scan chunks (8*4096 >= 30000)
#define NCV 25      // v-scan chunks (25*4096 >= 100000)

// ---------------------------------------------------------------------------
// Fused: blocks [0,HBLK) histogram both key arrays; blocks [HBLK,HBLK+XBLK)
// compute X0 = X @ Ww[0]^T + Wb[0]. Independent work -> concurrent instead of
// serial dispatches (R6).
// ---------------------------------------------------------------------------
__global__ __launch_bounds__(256) void x0_hist_kernel(
    const float* __restrict__ X, const float* __restrict__ Ww,
    const float* __restrict__ Wb, float* __restrict__ out0,
    const int* __restrict__ edges, const int* __restrict__ vertex,
    int* __restrict__ ecnt, int* __restrict__ vcnt)
{
    if (blockIdx.x < HBLK) {
        const int i = blockIdx.x * 256 + threadIdx.x;
        if (i < N_PAIRS) {
            atomicAdd(&ecnt[edges[i]], 1);
            atomicAdd(&vcnt[vertex[i]], 1);
        }
        return;
    }
    // ---- x0 part ----
    __shared__ float xs[TN][D];
    const int bid = blockIdx.x - HBLK;          // 0..XBLK-1
    const int wave = threadIdx.x >> 6;
    const int lane = threadIdx.x & 63;

    float w[64];
    const float* wrow = Ww + (size_t)lane * 64;
    #pragma unroll
    for (int i = 0; i < 64; i += 4) {
        float4 v = *(const float4*)(wrow + i);
        w[i] = v.x; w[i+1] = v.y; w[i+2] = v.z; w[i+3] = v.w;
    }
    const float b = Wb[lane];

    for (int base = bid * TN; base < N_NODES; base += XBLK * TN) {
        const int ntile = min(TN, N_NODES - base);
        __syncthreads();
        {
            int n = threadIdx.x >> 4;
            int c = (threadIdx.x & 15) << 2;
            if (n < ntile)
                *(float4*)&xs[n][c] = *(const float4*)&X[(size_t)(base + n) * D + c];
        }
        __syncthreads();
        #pragma unroll
        for (int q = 0; q < 4; ++q) {
            const int n = wave * 4 + q;
            if (n < ntile) {
                float acc = 0.f;
                #pragma unroll
                for (int i = 0; i < 64; ++i) acc = fmaf(xs[n][i], w[i], acc);
                out0[(size_t)(base + n) * D + lane] = acc + b;
            }
        }
    }
}

// ---------------------------------------------------------------------------
// 3-phase scan (R6: replaces 2-block scan2; 33 CUs instead of 2).
// Phase A: per-4096-chunk exclusive scan + chunk totals.
// Phase B: tiny serial scan of chunk totals (writes off[n] too).
// Phase C: add chunk base back to off and cur.
// ---------------------------------------------------------------------------
__device__ void scanA_body(const int* cnt, int* off, int* cur, int n,
                           int chunk, int* psum)
{
    __shared__ int wsum[16];
    const int lane = threadIdx.x & 63;
    const int wave = threadIdx.x >> 6;
    const int i0 = chunk * 4096 + threadIdx.x * 4;

    int x0 = 0, x1 = 0, x2 = 0, x3 = 0;
    if (i0 + 3 < n) {
        int4 v = *(const int4*)&cnt[i0];
        x0 = v.x; x1 = v.y; x2 = v.z; x3 = v.w;
    } else {
        if (i0     < n) x0 = cnt[i0];
        if (i0 + 1 < n) x1 = cnt[i0 + 1];
        if (i0 + 2 < n) x2 = cnt[i0 + 2];
        if (i0 + 3 < n) x3 = cnt[i0 + 3];
    }
    const int tsum = x0 + x1 + x2 + x3;
    int sc = tsum;
    #pragma unroll
    for (int s = 1; s < 64; s <<= 1) {
        int y = __shfl_up(sc, s);
        if (lane >= s) sc += y;
    }
    if (lane == 63) wsum[wave] = sc;
    __syncthreads();
    int wbase = 0;
    for (int w = 0; w < wave; ++w) wbase += wsum[w];
    const int excl = wbase + sc - tsum;
    const int o0 = excl, o1 = o0 + x0, o2 = o1 + x1, o3 = o2 + x2;
    if (i0 + 3 < n) {
        *(int4*)&off[i0] = make_int4(o0, o1, o2, o3);
        *(int4*)&cur[i0] = make_int4(o0, o1, o2, o3);
    } else {
        if (i0     < n) { off[i0]   = o0; cur[i0]   = o0; }
        if (i0 + 1 < n) { off[i0+1] = o1; cur[i0+1] = o1; }
        if (i0 + 2 < n) { off[i0+2] = o2; cur[i0+2] = o2; }
        if (i0 + 3 < n) { off[i0+3] = o3; cur[i0+3] = o3; }
    }
    if (threadIdx.x == 1023) psum[chunk] = wbase + sc;   // chunk total
}

__global__ __launch_bounds__(1024) void scanA_kernel(
    int* ecnt, int* eoff, int* vcnt, int* voff, int* psumE, int* psumV)
{
    if (blockIdx.x < NCE)
        scanA_body(ecnt, eoff, ecnt, EDGE_NUM, blockIdx.x, psumE);
    else
        scanA_body(vcnt, voff, vcnt, N_NODES, blockIdx.x - NCE, psumV);
}

__global__ __launch_bounds__(64) void scanB_kernel(
    int* psumE, int* psumV, int* eoff, int* voff)
{
    if (threadIdx.x == 0) {
        int base = 0;
        for (int c = 0; c < NCE; ++c) { int t = psumE[c]; psumE[c] = base; base += t; }
        eoff[EDGE_NUM] = base;
    }
    if (threadIdx.x == 1) {
        int base = 0;
        for (int c = 0; c < NCV; ++c) { int t = psumV[c]; psumV[c] = base; base += t; }
        voff[N_NODES] = base;
    }
}

__device__ void scanC_body(int* off, int* cur, int n, int chunk, const int* psum)
{
    const int base = psum[chunk];
    if (base == 0) return;
    const int i0 = chunk * 4096 + threadIdx.x * 4;
    if (i0 + 3 < n) {
        int4 o = *(const int4*)&off[i0];
        o.x += base; o.y += base; o.z += base; o.w += base;
        *(int4*)&off[i0] = o;
        *(int4*)&cur[i0] = o;
    } else {
        for (int i = i0; i < min(i0 + 4, n); ++i) {
            const int o = off[i] + base;
            off[i] = o; cur[i] = o;
        }
    }
}

__global__ __launch_bounds__(1024) void scanC_kernel(
    int* ecnt, int* eoff, int* vcnt, int* voff,
    const int* psumE, const int* psumV)
{
    if (blockIdx.x < NCE)
        scanC_body(eoff, ecnt, EDGE_NUM, blockIdx.x, psumE);
    else
        scanC_body(voff, vcnt, N_NODES, blockIdx.x - NCE, psumV);
}

// ---------------------------------------------------------------------------
// XCD-pinned fill (proven 132 us, R4). Scatter-writeback-bound: 3.2M random
// 4B stores; same-key slots written by one XCD partially merge in its L2
// (152 vs 198 MB single-pass). R5's partition alternative refuted (hot
// gcur atomics -> 817 us/pass).
// ---------------------------------------------------------------------------
__global__ __launch_bounds__(256) void fill_xcd_kernel(
    const int* __restrict__ edges, const int* __restrict__ vertex,
    int* __restrict__ ecur, int* __restrict__ vcur,
    int* __restrict__ evlist, int* __restrict__ velist)
{
    const int xcd = blockIdx.x & 7;
    const int grp = blockIdx.x >> 3;               // 0..NG-1
    const int elo = xcd * (EDGE_NUM / 8);
    const int ehi = elo + (EDGE_NUM / 8);
    const int vlo = xcd * (N_NODES / 8);
    const int vhi = vlo + (N_NODES / 8);

    for (int i = grp * 256 + threadIdx.x; i < N_PAIRS; i += NG * 256) {
        const int e = edges[i];
        const int v = vertex[i];
        if (e >= elo && e < ehi) evlist[atomicAdd(&ecur[e], 1)] = v;
        if (v >= vlo && v < vhi) velist[atomicAdd(&vcur[v], 1)] = e;
    }
}

// ---------------------------------------------------------------------------
// Kernel: per-edge gather. One wave per edge. Indices loaded 64-at-a-time
// per lane, broadcast via __shfl; inner loop unrolled 8-wide.
// R2 (kept, confirmed ~-87us): W_t staged in LDS (padded stride 65).
// ---------------------------------------------------------------------------
__global__ __launch_bounds__(256) void edge_gather_kernel(
    const float* __restrict__ X, const float* __restrict__ degV,
    const float* __restrict__ Ww, const float* __restrict__ Wb,
    const int* __restrict__ eoff, const int* __restrict__ evlist,
    float* __restrict__ Xe)
{
    __shared__ float Wlds[64 * 65];
    __shared__ float aLds[4][64];
    const int lane = threadIdx.x & 63;
    const int wave = threadIdx.x >> 6;
    const int e = blockIdx.x * 4 + wave;
    const int t = (e >= 10000) + (e >= 20000);   // uniform per block

    {
        const float* wsrc = Ww + (size_t)(t + 1) * 4096;
        for (int idx = threadIdx.x * 4; idx < 4096; idx += 256 * 4) {
            float4 v = *(const float4*)(wsrc + idx);
            const int r = idx >> 6, c = idx & 63;
            float* dst = &Wlds[r * 65 + c];
            dst[0] = v.x; dst[1] = v.y; dst[2] = v.z; dst[3] = v.w;
        }
    }
    __syncthreads();

    const float b = Wb[(t + 1) * 64 + lane];
    const int start = eoff[e], end = eoff[e + 1];
    const float* __restrict__ degt = degV + (size_t)t * N_NODES;
    const float* __restrict__ Xl = X + lane;

    float acc0 = 0.f, acc1 = 0.f, sdeg = 0.f;
    for (int j0 = start; j0 < end; j0 += 64) {
        const int m = min(64, end - j0);
        const int vv = (lane < m) ? evlist[j0 + lane] : 0;
        int j = 0;
        for (; j + 8 <= m; j += 8) {
            int v[8];
            #pragma unroll
            for (int u = 0; u < 8; ++u) v[u] = __shfl(vv, j + u);
            float f[8], s[8];
            #pragma unroll
            for (int u = 0; u < 8; ++u) f[u] = Xl[(size_t)v[u] * D];
            #pragma unroll
            for (int u = 0; u < 8; ++u) s[u] = degt[v[u]];
            #pragma unroll
            for (int u = 0; u < 8; u += 2) {
                acc0 = fmaf(s[u],     f[u],     acc0);
                acc1 = fmaf(s[u + 1], f[u + 1], acc1);
                sdeg += s[u] + s[u + 1];
            }
        }
        for (; j < m; ++j) {
            const int v = __shfl(vv, j);
            const float s = degt[v];
            acc0 = fmaf(s, Xl[(size_t)v * D], acc0);
            sdeg += s;
        }
    }
    aLds[wave][lane] = acc0 + acc1;

    float r = 0.f;
    #pragma unroll
    for (int i = 0; i < 64; ++i)
        r = fmaf(aLds[wave][i], Wlds[lane * 65 + i], r);
    r += sdeg * b;
    const int k = max(end - start, 1);
    Xe[(size_t)e * D + lane] = r / (float)k;
}

// ---------------------------------------------------------------------------
// Kernel: per-vertex gather + X0 add + L2 normalize + leaky relu (in place)
// ---------------------------------------------------------------------------
__global__ __launch_bounds__(256) void vertex_gather_kernel(
    const float* __restrict__ Xe, const int* __restrict__ voff,
    const int* __restrict__ velist, float* __restrict__ out)
{
    const int v = blockIdx.x * 4 + (threadIdx.x >> 6);
    const int lane = threadIdx.x & 63;
    const int start = voff[v], end = voff[v + 1];
    const float* __restrict__ Xel = Xe + lane;

    float acc0 = out[(size_t)v * D + lane];   // X0
    float acc1 = 0.f;
    for (int j0 = start; j0 < end; j0 += 64) {
        const int m = min(64, end - j0);
        const int ee = (lane < m) ? velist[j0 + lane] : 0;
        int j = 0;
        for (; j + 8 <= m; j += 8) {
            int e[8];
            #pragma unroll
            for (int u = 0; u < 8; ++u) e[u] = __shfl(ee, j + u);
            float f[8];
            #pragma unroll
            for (int u = 0; u < 8; ++u) f[u] = Xel[(size_t)e[u] * D];
            #pragma unroll
            for (int u = 0; u < 8; u += 2) {
                acc0 += f[u];
                acc1 += f[u + 1];
            }
        }
        for (; j < m; ++j) {
            const int e = __shfl(ee, j);
            acc0 += Xel[(size_t)e * D];
        }
    }
    const float acc = acc0 + acc1;

    float ss = acc * acc;
    #pragma unroll
    for (int off = 1; off < 64; off <<= 1) ss += __shfl_xor(ss, off);
    const float rn = sqrtf(ss);
    const float scale = (rn == 0.f) ? 0.f : 1.f / rn;
    const float y = acc * scale;
    out[(size_t)v * D + lane] = (y > 0.f) ? y : NEG_SLOPE * y;
}

// ---------------------------------------------------------------------------
extern "C" void kernel_launch(void* const* d_in, const int* in_sizes, int n_in,
                              void* d_out, int out_size, void* d_ws, size_t ws_size,
                              hipStream_t stream)
{
    const float* X      = (const float*)d_in[0];   // (100000, 64)
    const float* degV   = (const float*)d_in[1];   // (3, 100000, 1)
    const float* Ww     = (const float*)d_in[2];   // (4, 64, 64)
    const float* Wb     = (const float*)d_in[3];   // (4, 64)
    const int*   vertex = (const int*)d_in[4];     // (1600000,)
    const int*   edges  = (const int*)d_in[5];     // (1600000,)
    float* out = (float*)d_out;                    // (100000, 64)

    // workspace layout (~21.5 MB)
    float* Xe    = (float*)d_ws;              // 1,920,000 f32 (7.68 MB)
    int*   ib    = (int*)(Xe + 1920000);
    int* eoff    = ib;                        // 30001 (pad to 30004)
    int* ecur    = ib + 30004;                // 30000 (pad to 30004)
    int* voff    = ib + 60008;                // 100001 (pad to 100004)
    int* vcur    = ib + 160012;               // 100000
    int* psumE   = ib + 260012;               // 8  (pad to 16)
    int* psumV   = ib + 260028;               // 25 (pad to 36)
    int* evlist  = ib + 260064;               // 1,600,000
    int* velist  = ib + 1860064;              // 1,600,000

    // zero the counter region (eoff..vcur inclusive; psum* overwritten by scanA)
    hipMemsetAsync(ib, 0, (size_t)260012 * sizeof(int), stream);

    // hist (blocks 0..6249) + x0 (blocks 6250..7273), concurrent
    x0_hist_kernel<<<HBLK + XBLK, 256, 0, stream>>>(
        X, Ww, Wb, out, edges, vertex, ecur, vcur);

    scanA_kernel<<<NCE + NCV, 1024, 0, stream>>>(ecur, eoff, vcur, voff,
                                                 psumE, psumV);
    scanB_kernel<<<1, 64, 0, stream>>>(psumE, psumV, eoff, voff);
    scanC_kernel<<<NCE + NCV, 1024, 0, stream>>>(ecur, eoff, vcur, voff,
                                                 psumE, psumV);

    fill_xcd_kernel<<<8 * NG, 256, 0, stream>>>(edges, vertex, ecur, vcur,
                                                evlist, velist);

    edge_gather_kernel<<<EDGE_NUM / 4, 256, 0, stream>>>(
        X, degV, Ww, Wb, eoff, evlist, Xe);

    vertex_gather_kernel<<<N_NODES / 4, 256, 0, stream>>>(Xe, voff, velist, out);
}